// Round 1
// baseline (56.315 us; speedup 1.0000x reference)
//
#include <hip/hip_runtime.h>

// Analytic collapse of the 16-qubit circuit:
//   out[b][j] = prod_{i<=j} cos(params[i]) * cos(x[b][i])
// Derivation:
//   - state is a product state through all RX/RY gates
//   - CNOT chain is the prefix-XOR basis permutation: y_j = x_0^...^x_j
//   - <Z_j> = prod_{i<=j} <Z_i>_single ; <Z>_single of RY(t)RX(p)|0> = cos t * cos p

#define BATCH 64
#define NQ 16

__global__ __launch_bounds__(BATCH) void qlayer_kernel(
        const float* __restrict__ x,       // (BATCH, NQ)
        const float* __restrict__ params,  // (NQ,)
        float* __restrict__ out) {         // (BATCH, NQ)
    __shared__ float cp[NQ];
    const int t = threadIdx.x;
    if (t < NQ) cp[t] = cosf(params[t]);
    __syncthreads();

    const int b = t;  // one thread per batch row, single block of 64
    // vectorized load of this row's 16 floats (4x float4)
    float4 xv[4];
    const float4* xr = reinterpret_cast<const float4*>(x + b * NQ);
    #pragma unroll
    for (int q = 0; q < 4; ++q) xv[q] = xr[q];

    float o[NQ];
    float prod = 1.0f;
    #pragma unroll
    for (int i = 0; i < NQ; ++i) {
        const float xi = reinterpret_cast<const float*>(xv)[i];
        prod *= cp[i] * cosf(xi);
        o[i] = prod;
    }

    float4* orow = reinterpret_cast<float4*>(out + b * NQ);
    #pragma unroll
    for (int q = 0; q < 4; ++q)
        orow[q] = reinterpret_cast<const float4*>(o)[q];
}

extern "C" void kernel_launch(void* const* d_in, const int* in_sizes, int n_in,
                              void* d_out, int out_size, void* d_ws, size_t ws_size,
                              hipStream_t stream) {
    const float* x      = (const float*)d_in[0];  // (64,16) float32
    const float* params = (const float*)d_in[1];  // (16,)  float32
    float* out          = (float*)d_out;          // (64,16) float32
    qlayer_kernel<<<1, BATCH, 0, stream>>>(x, params, out);
}